// Round 5
// baseline (5646.841 us; speedup 1.0000x reference)
//
#include <hip/hip_runtime.h>
#include <stdint.h>

// ---------------- problem constants ----------------
#define EMBD   256
#define HID    512
#define KTOT   768            // EMB + HID
#define NCLS   50257
#define STEPS  512

// ---------------- persistent-kernel partition ----------------
// 64 blocks. Block = (superblock sb in 0..1, slice s in 0..31).
// Each block owns 16 hidden units (64 gate rows) for FOUR batch groups:
//   sub-step A: groups 4sb+0 (A-frag rows 0-7), 4sb+1 (rows 8-15)
//   sub-step B: groups 4sb+2, 4sb+3
// A and B are independent recurrence chains interleaved in time so the
// L3 store->load visibility latency of one hides behind the other's compute.
#define GB     8               // batches per group
#define UPITCH 776             // u row pitch in bf16 elems (768 + 8 pad)
#define RP     257             // red row pitch in floats (mod 32 == 1)

typedef float f32x4  __attribute__((ext_vector_type(4)));
typedef short bf16x8 __attribute__((ext_vector_type(8)));
typedef unsigned long long u64;

__device__ __forceinline__ unsigned bf16_rne(float f) {
  unsigned u = __float_as_uint(f);
  return (u + 0x7FFFu + ((u >> 16) & 1u)) >> 16;
}
__device__ __forceinline__ float bf16_to_f32(unsigned b) {
  return __uint_as_float(b << 16);
}

// ============ kernel 1: embedding gather + bf16 hi/lo pack ============
__global__ void emb_prep(const int* __restrict__ x, const float* __restrict__ emb,
                         unsigned* __restrict__ emb_hl) {
  int base = blockIdx.x * 4;
  int k = threadIdx.x;
  for (int it = 0; it < 4; ++it) {
    int tok = base + it;
    int id = x[tok];
    float w = emb[(size_t)id * EMBD + k];
    unsigned hb = bf16_rne(w);
    unsigned lb = bf16_rne(w - bf16_to_f32(hb));
    emb_hl[(size_t)tok * EMBD + k] = hb | (lb << 16);
  }
}

// ============ kernel 2: persistent LSTM recurrence ============
// h exchange: tagged u64 {tag=step+1 | hi|lo} relaxed agent-scope atomics
// (round-3 protocol, proven safe by the produce-after-consume argument).
// Exchange reads are wave-contiguous (batch=wave-row, lane spans units) and
// redistributed through LDS -- round 4 showed direct scattered A-frag loads
// regress 2x on coalescing.
__global__ __launch_bounds__(512, 2) void lstm_persist(
    const float* __restrict__ Ww, const float* __restrict__ Wb,
    const unsigned* __restrict__ emb_hl,
    u64* __restrict__ hbuf,
    unsigned short* __restrict__ h_hi, unsigned short* __restrict__ h_lo)
{
  __shared__ __align__(16) unsigned short u_hi[16 * UPITCH];
  __shared__ __align__(16) unsigned short u_lo[16 * UPITCH];
  __shared__ __align__(16) float red[2][32 * RP];   // [half][kwave*4+nt][lane*4+reg]

  const int tid  = threadIdx.x;
  const int wave = tid >> 6;
  const int lane = tid & 63;
  const int sb = blockIdx.x >> 5;   // superblock 0..1
  const int s  = blockIdx.x & 31;   // hidden slice (16 units)

  const int cn = lane & 15;
  const int qk = (lane >> 4) * 8;

  // ---- load W B-fragments into registers (once; shared by all 4 groups) ----
  bf16x8 whi[3][4], wlo[3][4];
#pragma unroll
  for (int i = 0; i < 3; ++i) {
    int k0 = (wave * 3 + i) * 32 + qk;
#pragma unroll
    for (int nt = 0; nt < 4; ++nt) {
      int row = nt * 512 + s * 16 + cn;
      const float* src = Ww + (size_t)row * KTOT + k0;
      float4 w0 = *(const float4*)src;
      float4 w1 = *(const float4*)(src + 4);
      float wv[8] = {w0.x, w0.y, w0.z, w0.w, w1.x, w1.y, w1.z, w1.w};
#pragma unroll
      for (int j = 0; j < 8; ++j) {
        unsigned hb = bf16_rne(wv[j]);
        unsigned lb = bf16_rne(wv[j] - bf16_to_f32(hb));
        whi[i][nt][j] = (short)hb;
        wlo[i][nt][j] = (short)lb;
      }
    }
  }

  const float bias = Wb[(lane >> 4) * 512 + s * 16 + (lane & 15)];

  float Cst[2][2] = {{0.f, 0.f}, {0.f, 0.f}};  // [half][m-half], lanes<16

  for (int step = 0; step < STEPS; ++step) {
#pragma unroll
    for (int half = 0; half < 2; ++half) {
      const int g0 = sb * 4 + half * 2;
      const int g1 = g0 + 1;

      // ---- fire h loads: wave stages batch `wave` of g0 (row wave) and of
      //      g1 (row 8+wave); lane covers 8 units -> fully coalesced ----
      const u64* hp0 = hbuf + ((size_t)(g0 * 2 + (step & 1)) * GB + wave) * HID + lane * 8;
      const u64* hp1 = hbuf + ((size_t)(g1 * 2 + (step & 1)) * GB + wave) * HID + lane * 8;
      u64 v0[8], v1[8];
#pragma unroll
      for (int j = 0; j < 8; ++j) {
        v0[j] = __hip_atomic_load(&hp0[j], __ATOMIC_RELAXED, __HIP_MEMORY_SCOPE_AGENT);
        v1[j] = __hip_atomic_load(&hp1[j], __ATOMIC_RELAXED, __HIP_MEMORY_SCOPE_AGENT);
      }

      // ---- emb stage (overlaps h-load latency): thread covers row tid>>5,
      //      8 consecutive u32 ----
      {
        const int r = tid >> 5;
        const int gbat = (r < 8 ? g0 : g1) * GB + (r & 7);
        const unsigned* ep = emb_hl + ((size_t)gbat * STEPS + step) * EMBD + (tid & 31) * 8;
        uint4 a = *(const uint4*)ep;
        uint4 b = *(const uint4*)(ep + 4);
        uint4 hv, lv;
        hv.x = (a.x & 0xFFFFu) | ((a.y & 0xFFFFu) << 16);
        hv.y = (a.z & 0xFFFFu) | ((a.w & 0xFFFFu) << 16);
        hv.z = (b.x & 0xFFFFu) | ((b.y & 0xFFFFu) << 16);
        hv.w = (b.z & 0xFFFFu) | ((b.w & 0xFFFFu) << 16);
        lv.x = (a.x >> 16) | (a.y & 0xFFFF0000u);
        lv.y = (a.z >> 16) | (a.w & 0xFFFF0000u);
        lv.z = (b.x >> 16) | (b.y & 0xFFFF0000u);
        lv.w = (b.z >> 16) | (b.w & 0xFFFF0000u);
        *(uint4*)&u_hi[r * UPITCH + (tid & 31) * 8] = hv;
        *(uint4*)&u_lo[r * UPITCH + (tid & 31) * 8] = lv;
      }

      // ---- tag poll (coalesced retries) ----
      {
        const unsigned want = (unsigned)step;
        while (true) {
          bool ok = true;
#pragma unroll
          for (int j = 0; j < 8; ++j) {
            ok &= ((unsigned)(v0[j] >> 32) == want);
            ok &= ((unsigned)(v1[j] >> 32) == want);
          }
          if (ok) break;
          __builtin_amdgcn_s_sleep(1);
#pragma unroll
          for (int j = 0; j < 8; ++j) {
            v0[j] = __hip_atomic_load(&hp0[j], __ATOMIC_RELAXED, __HIP_MEMORY_SCOPE_AGENT);
            v1[j] = __hip_atomic_load(&hp1[j], __ATOMIC_RELAXED, __HIP_MEMORY_SCOPE_AGENT);
          }
        }
      }

      // ---- unpack + stage h into u rows wave / 8+wave ----
      {
        bf16x8 hh, hl;
#pragma unroll
        for (int j = 0; j < 8; ++j) {
          unsigned w32 = (unsigned)v0[j];
          hh[j] = (short)(w32 & 0xFFFFu);
          hl[j] = (short)(w32 >> 16);
        }
        *(bf16x8*)&u_hi[wave * UPITCH + EMBD + lane * 8] = hh;
        *(bf16x8*)&u_lo[wave * UPITCH + EMBD + lane * 8] = hl;
#pragma unroll
        for (int j = 0; j < 8; ++j) {
          unsigned w32 = (unsigned)v1[j];
          hh[j] = (short)(w32 & 0xFFFFu);
          hl[j] = (short)(w32 >> 16);
        }
        *(bf16x8*)&u_hi[(8 + wave) * UPITCH + EMBD + lane * 8] = hh;
        *(bf16x8*)&u_lo[(8 + wave) * UPITCH + EMBD + lane * 8] = hl;
      }
      __syncthreads();

      // ---- gates = u @ W_sliceT : MFMA, k-split 8 ways over waves ----
      f32x4 acc[4] = {{0.f,0.f,0.f,0.f},{0.f,0.f,0.f,0.f},
                      {0.f,0.f,0.f,0.f},{0.f,0.f,0.f,0.f}};
#pragma unroll
      for (int i = 0; i < 3; ++i) {
        int k0 = (wave * 3 + i) * 32 + qk;
        int m = lane & 15;
        bf16x8 ahi = *(const bf16x8*)&u_hi[m * UPITCH + k0];
        bf16x8 alo = *(const bf16x8*)&u_lo[m * UPITCH + k0];
#pragma unroll
        for (int nt = 0; nt < 4; ++nt) {
          acc[nt] = __builtin_amdgcn_mfma_f32_16x16x32_bf16(ahi, whi[i][nt], acc[nt], 0, 0, 0);
          acc[nt] = __builtin_amdgcn_mfma_f32_16x16x32_bf16(ahi, wlo[i][nt], acc[nt], 0, 0, 0);
          acc[nt] = __builtin_amdgcn_mfma_f32_16x16x32_bf16(alo, whi[i][nt], acc[nt], 0, 0, 0);
        }
      }
      float* rp = red[half];
#pragma unroll
      for (int nt = 0; nt < 4; ++nt)
        *(f32x4*)&rp[(wave * 4 + nt) * RP + lane * 4] = acc[nt];
      __syncthreads();

      // ---- reduce: thread owns gate-row n=lane for m0=wave and m1=wave+8 ----
      const int tq = lane >> 4;
      const int m0 = wave, m1 = wave + 8;
      const int rb0 = ((((m0 >> 2) << 4) | (lane & 15)) << 2) + (m0 & 3);
      const int rb1 = ((((m1 >> 2) << 4) | (lane & 15)) << 2) + (m1 & 3);
      float gs0 = bias, gs1 = bias;
#pragma unroll
      for (int w = 0; w < 8; ++w) {
        gs0 += rp[(w * 4 + tq) * RP + rb0];
        gs1 += rp[(w * 4 + tq) * RP + rb1];
      }

      // ---- nonlinearities: lanes 0-15 f, 16-31 i, 32-47 o, 48-63 c~ ----
      float scl = (lane >= 48) ? 2.0f : 1.0f;
      float y0 = 1.0f / (1.0f + __expf(-gs0 * scl));
      float y1 = 1.0f / (1.0f + __expf(-gs1 * scl));
      float a0 = (lane >= 48) ? (2.0f * y0 - 1.0f) : y0;
      float a1 = (lane >= 48) ? (2.0f * y1 - 1.0f) : y1;
      float ig0 = __shfl(a0, lane + 16), og0 = __shfl(a0, lane + 32), cg0 = __shfl(a0, lane + 48);
      float ig1 = __shfl(a1, lane + 16), og1 = __shfl(a1, lane + 32), cg1 = __shfl(a1, lane + 48);
      if (lane < 16) {
        const int npar = (step + 1) & 1;
        // m0 -> group g0, batch=wave, unit=s*16+lane
        {
          float C = a0 * Cst[half][0] + ig0 * cg0;
          Cst[half][0] = C;
          float t2 = 1.0f / (1.0f + __expf(-2.0f * C));
          float hv = og0 * (2.0f * t2 - 1.0f);
          unsigned hb = bf16_rne(hv);
          unsigned lb = bf16_rne(hv - bf16_to_f32(hb));
          u64 pack = ((u64)(unsigned)(step + 1) << 32) | (u64)(hb | (lb << 16));
          __hip_atomic_store(
              &hbuf[((size_t)(g0 * 2 + npar) * GB + wave) * HID + s * 16 + lane],
              pack, __ATOMIC_RELAXED, __HIP_MEMORY_SCOPE_AGENT);
          if (step == STEPS - 1) {
            int m = g0 * GB + wave, k = s * 16 + lane;
            h_hi[m * HID + k] = (unsigned short)hb;
            h_lo[m * HID + k] = (unsigned short)lb;
          }
        }
        // m1 -> group g1
        {
          float C = a1 * Cst[half][1] + ig1 * cg1;
          Cst[half][1] = C;
          float t2 = 1.0f / (1.0f + __expf(-2.0f * C));
          float hv = og1 * (2.0f * t2 - 1.0f);
          unsigned hb = bf16_rne(hv);
          unsigned lb = bf16_rne(hv - bf16_to_f32(hb));
          u64 pack = ((u64)(unsigned)(step + 1) << 32) | (u64)(hb | (lb << 16));
          __hip_atomic_store(
              &hbuf[((size_t)(g1 * 2 + npar) * GB + wave) * HID + s * 16 + lane],
              pack, __ATOMIC_RELAXED, __HIP_MEMORY_SCOPE_AGENT);
          if (step == STEPS - 1) {
            int m = g1 * GB + wave, k = s * 16 + lane;
            h_hi[m * HID + k] = (unsigned short)hb;
            h_lo[m * HID + k] = (unsigned short)lb;
          }
        }
      }
      // no trailing barrier: next sub-step's staging barrier protects u;
      // red[half] WAR is covered by the intervening barriers (see comments)
    }
  }
}

// ============ kernel 3: out = h_final @ fcT + bias (MFMA hi/lo) ============
__device__ __forceinline__ void cvt8(const float4& a, const float4& b,
                                     bf16x8& hi, bf16x8& lo) {
  float v[8] = {a.x, a.y, a.z, a.w, b.x, b.y, b.z, b.w};
#pragma unroll
  for (int j = 0; j < 8; ++j) {
    unsigned hb = bf16_rne(v[j]);
    hi[j] = (short)hb;
    lo[j] = (short)bf16_rne(v[j] - bf16_to_f32(hb));
  }
}

__global__ __launch_bounds__(512) void fc_mfma(
    const unsigned short* __restrict__ h_hi, const unsigned short* __restrict__ h_lo,
    const float* __restrict__ fcw, const float* __restrict__ fcb,
    float* __restrict__ out)
{
  const int tid = threadIdx.x, wave = tid >> 6, lane = tid & 63;
  const int cn = lane & 15;
  const int qk = (lane >> 4) * 8;
  const int cls  = blockIdx.x * 128 + wave * 16 + cn;
  const int clsc = cls < NCLS ? cls : NCLS - 1;

  f32x4 acc[4] = {{0.f,0.f,0.f,0.f},{0.f,0.f,0.f,0.f},
                  {0.f,0.f,0.f,0.f},{0.f,0.f,0.f,0.f}};
#pragma unroll 2
  for (int kt = 0; kt < 16; ++kt) {
    int k0 = kt * 32 + qk;
    const float* bp = fcw + (size_t)clsc * HID + k0;
    float4 b0 = *(const float4*)bp;
    float4 b1 = *(const float4*)(bp + 4);
    bf16x8 bhi, blo;
    cvt8(b0, b1, bhi, blo);
#pragma unroll
    for (int mt = 0; mt < 4; ++mt) {
      bf16x8 ahi = *(const bf16x8*)&h_hi[(size_t)(mt * 16 + cn) * HID + k0];
      bf16x8 alo = *(const bf16x8*)&h_lo[(size_t)(mt * 16 + cn) * HID + k0];
      acc[mt] = __builtin_amdgcn_mfma_f32_16x16x32_bf16(ahi, bhi, acc[mt], 0, 0, 0);
      acc[mt] = __builtin_amdgcn_mfma_f32_16x16x32_bf16(ahi, blo, acc[mt], 0, 0, 0);
      acc[mt] = __builtin_amdgcn_mfma_f32_16x16x32_bf16(alo, bhi, acc[mt], 0, 0, 0);
    }
  }
  if (cls < NCLS) {
    float bias = fcb[cls];
#pragma unroll
    for (int mt = 0; mt < 4; ++mt)
#pragma unroll
      for (int j = 0; j < 4; ++j) {
        int m = mt * 16 + (lane >> 4) * 4 + j;
        out[(size_t)m * NCLS + cls] = acc[mt][j] + bias;
      }
  }
}

// ============ launcher ============
extern "C" void kernel_launch(void* const* d_in, const int* in_sizes, int n_in,
                              void* d_out, int out_size, void* d_ws, size_t ws_size,
                              hipStream_t stream) {
  const int*   x   = (const int*)d_in[0];
  const float* emb = (const float*)d_in[1];
  const float* Ww  = (const float*)d_in[2];
  const float* Wb  = (const float*)d_in[3];
  const float* fcw = (const float*)d_in[4];
  const float* fcb = (const float*)d_in[5];
  float* out = (float*)d_out;

  // workspace carve-up
  char* ws = (char*)d_ws;
  u64*            hbuf   = (u64*)ws;                          // 524,288 B (8g x 2par x 8b x 512u x 8B)
  unsigned short* h_hi   = (unsigned short*)(ws + 524288);    //  65,536 B
  unsigned short* h_lo   = (unsigned short*)(ws + 524288 + 65536);
  unsigned*       emb_hl = (unsigned*)(ws + 524288 + 131072); // 33.5 MB

  // zero h exchange buffer: tag=0 == "h for step 0 valid and zero"
  hipMemsetAsync(hbuf, 0, 524288, stream);

  emb_prep<<<8192, 256, 0, stream>>>(x, emb, emb_hl);

  void* args[] = { (void*)&Ww, (void*)&Wb, (void*)&emb_hl,
                   (void*)&hbuf, (void*)&h_hi, (void*)&h_lo };
  hipLaunchCooperativeKernel((void*)lstm_persist, dim3(64), dim3(512),
                             args, 0, stream);

  fc_mfma<<<(NCLS + 127) / 128, 512, 0, stream>>>(h_hi, h_lo, fcw, fcb, out);
}

// Round 6
// 5396.666 us; speedup vs baseline: 1.0464x; 1.0464x over previous
//
#include <hip/hip_runtime.h>
#include <stdint.h>

// ---------------- problem constants ----------------
#define EMBD   256
#define HID    512
#define KTOT   768            // EMB + HID
#define NCLS   50257
#define STEPS  512

// ---------------- persistent-kernel partition (round-3 shape) ----------------
#define NGROUP 8               // batch groups
#define GB     8               // batches per group
#define BPG    32              // blocks per group (hidden split)
#define HS     16              // hidden units per block -> 64 gate rows
#define UP     104             // wave-region per-batch pitch in u16 (96 data + 8 pad)
#define RP     129             // red row pitch in floats (mod 32 == 1 -> conflict-free)

typedef float f32x4  __attribute__((ext_vector_type(4)));
typedef short bf16x8 __attribute__((ext_vector_type(8)));
typedef unsigned long long u64;

__device__ __forceinline__ unsigned bf16_rne(float f) {
  unsigned u = __float_as_uint(f);
  return (u + 0x7FFFu + ((u >> 16) & 1u)) >> 16;
}
__device__ __forceinline__ float bf16_to_f32(unsigned b) {
  return __uint_as_float(b << 16);
}

// ============ kernel 1: embedding gather + bf16 hi/lo pack ============
__global__ void emb_prep(const int* __restrict__ x, const float* __restrict__ emb,
                         unsigned* __restrict__ emb_hl) {
  int base = blockIdx.x * 4;
  int k = threadIdx.x;
  for (int it = 0; it < 4; ++it) {
    int tok = base + it;
    int id = x[tok];
    float w = emb[(size_t)id * EMBD + k];
    unsigned hb = bf16_rne(w);
    unsigned lb = bf16_rne(w - bf16_to_f32(hb));
    emb_hl[(size_t)tok * EMBD + k] = hb | (lb << 16);
  }
}

// ============ kernel 2: persistent LSTM recurrence ============
// 256 blocks (cooperative), 512 thr. g = blockIdx&7 (XCD-local under rr, perf
// only). h exchange: tagged u64 {tag=step+1 | hi|lo}, relaxed agent-scope
// atomics (round-3 protocol; produce-after-consume proof holds with the single
// pre-store barrier). NEW vs round 3: each wave polls ONLY its own k-slice
// (units [64w,64w+64) -> 4 producer blocks, coalesced 64B/lane), stages into a
// WAVE-PRIVATE LDS region (lgkmcnt-ordered, no barrier), and computes its emb
// k-tile's 12 MFMAs before the h tag check. One block barrier per step.
__global__ __launch_bounds__(512, 1) void lstm_persist(
    const float* __restrict__ Ww, const float* __restrict__ Wb,
    const unsigned* __restrict__ emb_hl,
    u64* __restrict__ hbuf,
    unsigned short* __restrict__ h_hi, unsigned short* __restrict__ h_lo)
{
  // wave-private staging: [wave][batch 0..7][96 k-units + pad] hi/lo planes
  __shared__ __align__(16) unsigned short u_hi[8 * 8 * UP];
  __shared__ __align__(16) unsigned short u_lo[8 * 8 * UP];
  __shared__ __align__(16) float red[2][32 * RP];

  const int tid  = threadIdx.x;
  const int wave = tid >> 6;
  const int lane = tid & 63;
  const int g = blockIdx.x & 7;     // batch group 0..7
  const int s = blockIdx.x >> 3;    // hidden slice 0..31

  const int cn = lane & 15;
  const int qk = (lane >> 4) * 8;
  const int bb = lane >> 3;         // batch row this lane stages
  const int ii = lane & 7;          // chunk within row
  const int wbase = wave * (8 * UP);
  const int mb = lane & 7;          // clamped A-row for LDS reads (rows 8-15 mirror 0-7)

  // k-tiles of this wave: tile0 = emb k [32w,32w+32); tiles 1,2 = h units [64w,64w+64)
  const float bias = Wb[(lane >> 4) * 512 + s * HS + cn];

  // ---- load W B-fragments into registers (one time) ----
  bf16x8 whi[3][4], wlo[3][4];
#pragma unroll
  for (int i = 0; i < 3; ++i) {
    int kg = (i == 0) ? (wave * 32 + qk) : (EMBD + wave * 64 + (i - 1) * 32 + qk);
#pragma unroll
    for (int nt = 0; nt < 4; ++nt) {
      int row = nt * 512 + s * HS + cn;
      const float* src = Ww + (size_t)row * KTOT + kg;
      float4 w0 = *(const float4*)src;
      float4 w1 = *(const float4*)(src + 4);
      float wv[8] = {w0.x, w0.y, w0.z, w0.w, w1.x, w1.y, w1.z, w1.w};
#pragma unroll
      for (int j = 0; j < 8; ++j) {
        unsigned hb = bf16_rne(wv[j]);
        unsigned lb = bf16_rne(wv[j] - bf16_to_f32(hb));
        whi[i][nt][j] = (short)hb;
        wlo[i][nt][j] = (short)lb;
      }
    }
  }

  float Cst = 0.0f;  // cell state for (batch=wave, unit=lane) on lanes<16

  const unsigned* embg = emb_hl + (size_t)(g * GB + bb) * STEPS * EMBD + wave * 32 + ii * 4;
  u64* hg = hbuf + (size_t)g * 2 * GB * HID;

  __syncthreads();

  for (int step = 0; step < STEPS; ++step) {
    // ---- issue emb load (1x dwordx4) then h loads (8x u64, 64B/lane) ----
    uint4 ev = *(const uint4*)(embg + (size_t)step * EMBD);
    const u64* hp = hg + ((size_t)(step & 1) * GB + bb) * HID + 64 * wave + ii * 8;
    u64 hv[8];
#pragma unroll
    for (int j = 0; j < 8; ++j)
      hv[j] = __hip_atomic_load(&hp[j], __ATOMIC_RELAXED, __HIP_MEMORY_SCOPE_AGENT);

    // ---- stage emb into wave region (waits emb only; h stays in flight) ----
    {
      uint2 eh, el;
      eh.x = (ev.x & 0xFFFFu) | ((ev.y & 0xFFFFu) << 16);
      eh.y = (ev.z & 0xFFFFu) | ((ev.w & 0xFFFFu) << 16);
      el.x = (ev.x >> 16) | (ev.y & 0xFFFF0000u);
      el.y = (ev.z >> 16) | (ev.w & 0xFFFF0000u);
      *(uint2*)&u_hi[wbase + bb * UP + ii * 4] = eh;
      *(uint2*)&u_lo[wbase + bb * UP + ii * 4] = el;
    }

    // ---- emb A-frags + 12 MFMAs (hide h poll latency) ----
    f32x4 acc[4] = {{0.f,0.f,0.f,0.f},{0.f,0.f,0.f,0.f},
                    {0.f,0.f,0.f,0.f},{0.f,0.f,0.f,0.f}};
    {
      bf16x8 ahi = *(const bf16x8*)&u_hi[wbase + mb * UP + qk];
      bf16x8 alo = *(const bf16x8*)&u_lo[wbase + mb * UP + qk];
#pragma unroll
      for (int nt = 0; nt < 4; ++nt) {
        acc[nt] = __builtin_amdgcn_mfma_f32_16x16x32_bf16(ahi, whi[0][nt], acc[nt], 0, 0, 0);
        acc[nt] = __builtin_amdgcn_mfma_f32_16x16x32_bf16(ahi, wlo[0][nt], acc[nt], 0, 0, 0);
        acc[nt] = __builtin_amdgcn_mfma_f32_16x16x32_bf16(alo, whi[0][nt], acc[nt], 0, 0, 0);
      }
    }

    // ---- tag poll: this lane waits on exactly ONE producer block ----
    {
      const unsigned want = (unsigned)step;
      while (true) {
        bool ok = true;
#pragma unroll
        for (int j = 0; j < 8; ++j) ok &= ((unsigned)(hv[j] >> 32) == want);
        if (__all(ok)) break;
#pragma unroll
        for (int j = 0; j < 8; ++j)
          hv[j] = __hip_atomic_load(&hp[j], __ATOMIC_RELAXED, __HIP_MEMORY_SCOPE_AGENT);
      }
    }

    // ---- stage h into wave region ----
    {
      bf16x8 hh, hl;
#pragma unroll
      for (int j = 0; j < 8; ++j) {
        unsigned w32 = (unsigned)hv[j];
        hh[j] = (short)(w32 & 0xFFFFu);
        hl[j] = (short)(w32 >> 16);
      }
      *(bf16x8*)&u_hi[wbase + bb * UP + 32 + ii * 8] = hh;
      *(bf16x8*)&u_lo[wbase + bb * UP + 32 + ii * 8] = hl;
    }

    // ---- h A-frags + 24 MFMAs (wave-local; lgkmcnt orders LDS, no barrier) ----
#pragma unroll
    for (int i = 1; i < 3; ++i) {
      bf16x8 ahi = *(const bf16x8*)&u_hi[wbase + mb * UP + i * 32 + qk];
      bf16x8 alo = *(const bf16x8*)&u_lo[wbase + mb * UP + i * 32 + qk];
#pragma unroll
      for (int nt = 0; nt < 4; ++nt) {
        acc[nt] = __builtin_amdgcn_mfma_f32_16x16x32_bf16(ahi, whi[i][nt], acc[nt], 0, 0, 0);
        acc[nt] = __builtin_amdgcn_mfma_f32_16x16x32_bf16(ahi, wlo[i][nt], acc[nt], 0, 0, 0);
        acc[nt] = __builtin_amdgcn_mfma_f32_16x16x32_bf16(alo, whi[i][nt], acc[nt], 0, 0, 0);
      }
    }

    // ---- k-split partials -> red (parity double-buffered) ----
    float* rp = red[step & 1];
    if (lane < 32) {
#pragma unroll
      for (int nt = 0; nt < 4; ++nt)
        *(f32x4*)&rp[(wave * 4 + nt) * RP + lane * 4] = acc[nt];
    }
    __syncthreads();   // the ONLY barrier per step

    // ---- reduction: thread owns (batch=wave, gate=lane>>4, unit=lane&15) ----
    float gsum = bias;
    {
      int tq = lane >> 4;
      int rbase = ((((wave >> 2) << 4) | cn) << 2) + (wave & 3);
#pragma unroll
      for (int w = 0; w < 8; ++w)
        gsum += rp[(w * 4 + tq) * RP + rbase];
    }

    // ---- nonlinearities: lanes 0-15 f, 16-31 i, 32-47 o, 48-63 c~ ----
    float scl = (lane >= 48) ? 2.0f : 1.0f;
    float y = 1.0f / (1.0f + __expf(-gsum * scl));
    float act = (lane >= 48) ? (2.0f * y - 1.0f) : y;   // tanh via sigmoid
    float ig = __shfl(act, lane + 16);
    float og = __shfl(act, lane + 32);
    float cg = __shfl(act, lane + 48);
    if (lane < 16) {
      Cst = act * Cst + ig * cg;
      float t2 = 1.0f / (1.0f + __expf(-2.0f * Cst));
      float hv2 = og * (2.0f * t2 - 1.0f);
      unsigned hb = bf16_rne(hv2);
      unsigned lb = bf16_rne(hv2 - bf16_to_f32(hb));
      u64 pack = ((u64)(unsigned)(step + 1) << 32) | (u64)(hb | (lb << 16));
      __hip_atomic_store(
          &hg[((size_t)((step + 1) & 1) * GB + wave) * HID + s * HS + lane],
          pack, __ATOMIC_RELAXED, __HIP_MEMORY_SCOPE_AGENT);
      if (step == STEPS - 1) {
        int m = g * GB + wave, k = s * HS + lane;
        h_hi[m * HID + k] = (unsigned short)hb;
        h_lo[m * HID + k] = (unsigned short)lb;
      }
    }
    // no trailing barrier: u regions are wave-private; red is parity-buffered
  }
}

// ============ kernel 3: out = h_final @ fcT + bias (MFMA hi/lo) ============
__device__ __forceinline__ void cvt8(const float4& a, const float4& b,
                                     bf16x8& hi, bf16x8& lo) {
  float v[8] = {a.x, a.y, a.z, a.w, b.x, b.y, b.z, b.w};
#pragma unroll
  for (int j = 0; j < 8; ++j) {
    unsigned hb = bf16_rne(v[j]);
    hi[j] = (short)hb;
    lo[j] = (short)bf16_rne(v[j] - bf16_to_f32(hb));
  }
}

__global__ __launch_bounds__(512) void fc_mfma(
    const unsigned short* __restrict__ h_hi, const unsigned short* __restrict__ h_lo,
    const float* __restrict__ fcw, const float* __restrict__ fcb,
    float* __restrict__ out)
{
  const int tid = threadIdx.x, wave = tid >> 6, lane = tid & 63;
  const int cn = lane & 15;
  const int qk = (lane >> 4) * 8;
  const int cls  = blockIdx.x * 128 + wave * 16 + cn;
  const int clsc = cls < NCLS ? cls : NCLS - 1;

  f32x4 acc[4] = {{0.f,0.f,0.f,0.f},{0.f,0.f,0.f,0.f},
                  {0.f,0.f,0.f,0.f},{0.f,0.f,0.f,0.f}};
#pragma unroll 2
  for (int kt = 0; kt < 16; ++kt) {
    int k0 = kt * 32 + qk;
    const float* bp = fcw + (size_t)clsc * HID + k0;
    float4 b0 = *(const float4*)bp;
    float4 b1 = *(const float4*)(bp + 4);
    bf16x8 bhi, blo;
    cvt8(b0, b1, bhi, blo);
#pragma unroll
    for (int mt = 0; mt < 4; ++mt) {
      bf16x8 ahi = *(const bf16x8*)&h_hi[(size_t)(mt * 16 + cn) * HID + k0];
      bf16x8 alo = *(const bf16x8*)&h_lo[(size_t)(mt * 16 + cn) * HID + k0];
      acc[mt] = __builtin_amdgcn_mfma_f32_16x16x32_bf16(ahi, bhi, acc[mt], 0, 0, 0);
      acc[mt] = __builtin_amdgcn_mfma_f32_16x16x32_bf16(ahi, blo, acc[mt], 0, 0, 0);
      acc[mt] = __builtin_amdgcn_mfma_f32_16x16x32_bf16(alo, bhi, acc[mt], 0, 0, 0);
    }
  }
  if (cls < NCLS) {
    float bias = fcb[cls];
#pragma unroll
    for (int mt = 0; mt < 4; ++mt)
#pragma unroll
      for (int j = 0; j < 4; ++j) {
        int m = mt * 16 + (lane >> 4) * 4 + j;
        out[(size_t)m * NCLS + cls] = acc[mt][j] + bias;
      }
  }
}

// ============ launcher ============
extern "C" void kernel_launch(void* const* d_in, const int* in_sizes, int n_in,
                              void* d_out, int out_size, void* d_ws, size_t ws_size,
                              hipStream_t stream) {
  const int*   x   = (const int*)d_in[0];
  const float* emb = (const float*)d_in[1];
  const float* Ww  = (const float*)d_in[2];
  const float* Wb  = (const float*)d_in[3];
  const float* fcw = (const float*)d_in[4];
  const float* fcb = (const float*)d_in[5];
  float* out = (float*)d_out;

  // workspace carve-up
  char* ws = (char*)d_ws;
  u64*            hbuf   = (u64*)ws;                          // 524,288 B
  unsigned short* h_hi   = (unsigned short*)(ws + 524288);    //  65,536 B
  unsigned short* h_lo   = (unsigned short*)(ws + 524288 + 65536);
  unsigned*       emb_hl = (unsigned*)(ws + 524288 + 131072); // 33.5 MB

  // zero h exchange buffer: tag=0 == "h for step 0 valid and zero"
  hipMemsetAsync(hbuf, 0, 524288, stream);

  emb_prep<<<8192, 256, 0, stream>>>(x, emb, emb_hl);

  void* args[] = { (void*)&Ww, (void*)&Wb, (void*)&emb_hl,
                   (void*)&hbuf, (void*)&h_hi, (void*)&h_lo };
  hipLaunchCooperativeKernel((void*)lstm_persist, dim3(256), dim3(512),
                             args, 0, stream);

  fc_mfma<<<(NCLS + 127) / 128, 512, 0, stream>>>(h_hi, h_lo, fcw, fcb, out);
}